// Round 1
// baseline (558.492 us; speedup 1.0000x reference)
//
#include <hip/hip_runtime.h>

typedef __bf16 bf16;
typedef __attribute__((ext_vector_type(8))) __bf16 bf16x8;
typedef __attribute__((ext_vector_type(4))) __bf16 bf16x4;
typedef __attribute__((ext_vector_type(4))) float f32x4;

namespace {
constexpr int Bn = 2;
constexpr int T  = 16384;
constexpr int NL = 24;
constexpr int VOC = 259;
}

#define MFMA_B16(a, b, c) __builtin_amdgcn_mfma_f32_16x16x32_bf16((a), (b), (c), 0, 0, 0)

// ---------- prep: conv+cond weights, frag-ordered ----------
__global__ void prep_wconv_k(const float* __restrict__ cw, const float* __restrict__ dw,
                             bf16* __restrict__ W2) {
  int total = NL * 61440;
  for (int idx = blockIdx.x * 256 + threadIdx.x; idx < total; idx += gridDim.x * 256) {
    int l = idx / 61440; int r = idx % 61440;
    int s = r >> 12; int of = (r >> 9) & 7; int lane = (r >> 3) & 63; int j = r & 7;
    int o = of * 16 + (lane & 15);
    int kk = (lane >> 4) * 8 + j;
    float v;
    if (s < 12) { int k = s >> 2; int c = (s & 3) * 32 + kk; v = cw[((l * 128 + o) * 128 + c) * 3 + k]; }
    else        { int cc = (s - 12) * 32 + kk; v = (cc < 80) ? dw[(l * 128 + o) * 80 + cc] : 0.f; }
    W2[idx] = (bf16)v;
  }
}

// ---------- prep: fc1 / enc / emb bf16 copies + fc2 B-frag order (24 o-tiles) ----------
__global__ void prep_misc_k(const float* __restrict__ fc1w, const float* __restrict__ encw,
                            const float* __restrict__ emb, const float* __restrict__ fc2w,
                            bf16* __restrict__ fc1wb, bf16* __restrict__ encwb,
                            bf16* __restrict__ embb, bf16* __restrict__ w2f) {
  const int n1 = 65536, n2 = 16384, n3 = 33152, n4 = 196608;
  int total = n1 + n2 + n3 + n4;
  for (int idx = blockIdx.x * 256 + threadIdx.x; idx < total; idx += gridDim.x * 256) {
    if (idx < n1) { fc1wb[idx] = (bf16)fc1w[idx]; }
    else if (idx < n1 + n2) { int i = idx - n1; encwb[i] = (bf16)encw[i]; }
    else if (idx < n1 + n2 + n3) { int i = idx - n1 - n2; embb[i] = (bf16)emb[i]; }
    else {
      int r = idx - n1 - n2 - n3;
      int s = r / 12288; int r2 = r % 12288;
      int ot = r2 >> 9; int lane = (r2 >> 3) & 63; int j = r & 7;
      int o = ot * 16 + (lane & 15);
      int f = s * 32 + (lane >> 4) * 8 + j;
      w2f[r] = (bf16)((o < VOC) ? fc2w[o * 512 + f] : 0.f);
    }
  }
}

// ---------- upsample stages 1..3 (f32) ----------
__global__ void ups_stage_k(const float* __restrict__ in, float* __restrict__ out,
                            const float* __restrict__ W, const float* __restrict__ bptr, int Win) {
  int Wout = Win * 4;
  int total = Bn * 80 * Wout;
  float bias = *bptr;
  for (int idx = blockIdx.x * 256 + threadIdx.x; idx < total; idx += gridDim.x * 256) {
    int w = idx % Wout; int rest = idx / Wout;
    int hrow = rest % 80; int b = rest / 80;
    int win = w >> 2; int kw = w & 3;
    float acc = bias;
#pragma unroll
    for (int kh = 0; kh < 3; ++kh) {
      int hr = hrow + 1 - kh;
      if (hr >= 0 && hr < 80) acc += in[(b * 80 + hr) * Win + win] * W[kh * 4 + kw];
    }
    out[idx] = fmaxf(acc, 0.f);
  }
}

// ---------- fused upsample stage 4 + transpose -> cuT (b,t,96) bf16 ----------
__global__ void ups4_cuT_k(const float* __restrict__ in, const float* __restrict__ W,
                           const float* __restrict__ bptr, bf16* __restrict__ cuT) {
  int total = Bn * T * 96;
  float bias = *bptr;
  for (int idx = blockIdx.x * 256 + threadIdx.x; idx < total; idx += gridDim.x * 256) {
    int cc = idx % 96; int rest = idx / 96;
    int t = rest % T; int b = rest / T;
    float v = 0.f;
    if (cc < 80) {
      int win = t >> 2, kw = t & 3;
      float acc = bias;
#pragma unroll
      for (int kh = 0; kh < 3; ++kh) {
        int hr = cc + 1 - kh;
        if (hr >= 0 && hr < 80) acc += in[(b * 80 + hr) * 4096 + win] * W[kh * 4 + kw];
      }
      v = fmaxf(acc, 0.f);
    }
    cuT[idx] = (bf16)v;
  }
}

// ---------- encode: h = relu(enc_w @ emb[x] + enc_b) -> hbt (b,t,128) via LDS bounce ----------
__global__ __launch_bounds__(256, 2) void encode_k(
    const int* __restrict__ x, const bf16* __restrict__ embb, const bf16* __restrict__ encwb,
    const float* __restrict__ encb, bf16* __restrict__ hbt) {
  __shared__ char Eb[16384];   // 64 rows x 256B, XOR-swizzled 16B slots
  int t0 = blockIdx.x * 64, b = blockIdx.y;
  int tid = threadIdx.x, lane = tid & 63, wid = tid >> 6, wr = wid >> 1, wc = wid & 1;
  int lr = lane & 15, lk = lane >> 4;
  int tb = t0 + wc * 32;
  int xi[2];
#pragma unroll
  for (int n = 0; n < 2; ++n) xi[n] = x[b * T + tb + n * 16 + lr];
  f32x4 acc[4][2] = {};
#pragma unroll
  for (int s = 0; s < 4; ++s) {
    bf16x8 a[4], bb[2];
#pragma unroll
    for (int m = 0; m < 4; ++m) a[m] = *(const bf16x8*)(encwb + (wr * 64 + m * 16 + lr) * 128 + s * 32 + lk * 8);
#pragma unroll
    for (int n = 0; n < 2; ++n) bb[n] = *(const bf16x8*)(embb + xi[n] * 128 + s * 32 + lk * 8);
#pragma unroll
    for (int m = 0; m < 4; ++m)
#pragma unroll
      for (int n = 0; n < 2; ++n) acc[m][n] = MFMA_B16(a[m], bb[n], acc[m][n]);
  }
#pragma unroll
  for (int m = 0; m < 4; ++m)
#pragma unroll
    for (int n = 0; n < 2; ++n) {
      int obase = wr * 64 + m * 16 + lk * 4;
      int row = wc * 32 + n * 16 + lr;
      bf16x4 p;
#pragma unroll
      for (int r = 0; r < 4; ++r) p[r] = (bf16)fmaxf(acc[m][n][r] + encb[obase + r], 0.f);
      int byteo = obase * 2;
      int slot = ((byteo >> 4) ^ (row & 7)) & 15;
      *(bf16x4*)(Eb + row * 256 + (slot << 4) + (byteo & 15)) = p;
    }
  __syncthreads();
  const size_t btb = (size_t)b * T;
  for (int u = tid; u < 1024; u += 256) {
    int row = u >> 4, slot = u & 15;
    uint4 v = *(const uint4*)(Eb + row * 256 + ((((slot) ^ (row & 7)) & 15) << 4));
    *(uint4*)(hbt + (btb + t0 + row) * 128 + slot * 8) = v;
  }
}

// ---------- helpers ----------
// conv over 12 K-steps, B-fragments straight from global hbt (L2/L3-resident).
template <int D, bool GUARD>
__device__ __forceinline__ void convA(const bf16* __restrict__ hin, size_t btb, int tfirst,
                                      const bf16* __restrict__ W,
                                      f32x4 (&acc)[4][2], int lane, int lr, int lk, int wr) {
#pragma unroll
  for (int s = 0; s < 12; ++s) {
    const int k = s >> 2, shift = (k - 2) * D;
    const int co = (s & 3) * 32 + lk * 8;
    bf16x8 a[4], bb[2];
#pragma unroll
    for (int m = 0; m < 4; ++m) a[m] = *(const bf16x8*)(W + ((s * 8 + wr * 4 + m) * 64 + lane) * 8);
#pragma unroll
    for (int n = 0; n < 2; ++n) {
      int t = tfirst + n * 16 + lr + shift;
      if (GUARD) {
        int tc = (t < 0) ? 0 : t;
        bf16x8 v = *(const bf16x8*)(hin + (btb + tc) * 128 + co);
        bf16x8 z = {};
        bb[n] = (t < 0) ? z : v;
      } else {
        bb[n] = *(const bf16x8*)(hin + (btb + t) * 128 + co);
      }
    }
#pragma unroll
    for (int m = 0; m < 4; ++m)
#pragma unroll
      for (int n = 0; n < 2; ++n) acc[m][n] = MFMA_B16(a[m], bb[n], acc[m][n]);
  }
}

// conv over 12 K-steps, B-fragments from XOR-swizzled LDS tile (rows of 256B).
template <int D>
__device__ __forceinline__ void convL(const char* __restrict__ L, int rowbase,
                                      const bf16* __restrict__ W,
                                      f32x4 (&acc)[4][2], int lane, int lr, int lk, int wr) {
#pragma unroll
  for (int s = 0; s < 12; ++s) {
    const int k = s >> 2, shift = (k - 2) * D, sb = (s & 3) * 4;
    bf16x8 a[4], bb[2];
#pragma unroll
    for (int m = 0; m < 4; ++m) a[m] = *(const bf16x8*)(W + ((s * 8 + wr * 4 + m) * 64 + lane) * 8);
#pragma unroll
    for (int n = 0; n < 2; ++n) {
      int row = rowbase + n * 16 + lr + shift;
      int slot = ((sb + lk) ^ (row & 7)) & 15;
      bb[n] = *(const bf16x8*)(L + row * 256 + slot * 16);
    }
#pragma unroll
    for (int m = 0; m < 4; ++m)
#pragma unroll
      for (int n = 0; n < 2; ++n) acc[m][n] = MFMA_B16(a[m], bb[n], acc[m][n]);
  }
}

__device__ __forceinline__ void cond3g(const bf16* __restrict__ cuT, size_t btb, int tfirst,
                                       const bf16* __restrict__ W,
                                       f32x4 (&acc)[4][2], int lane, int lr, int lk, int wr) {
#pragma unroll
  for (int s = 12; s < 15; ++s) {
    bf16x8 a[4], bb[2];
#pragma unroll
    for (int m = 0; m < 4; ++m) a[m] = *(const bf16x8*)(W + ((s * 8 + wr * 4 + m) * 64 + lane) * 8);
#pragma unroll
    for (int n = 0; n < 2; ++n) {
      int t = tfirst + n * 16 + lr;
      if (t < 0) t = 0;
      bb[n] = *(const bf16x8*)(cuT + (btb + t) * 96 + (s - 12) * 32 + lk * 8);
    }
#pragma unroll
    for (int m = 0; m < 4; ++m)
#pragma unroll
      for (int n = 0; n < 2; ++n) acc[m][n] = MFMA_B16(a[m], bb[n], acc[m][n]);
  }
}

__device__ __forceinline__ void relu_cb4(f32x4 (&acc)[4][2], const float* __restrict__ cbs,
                                         int wr, int lk) {
#pragma unroll
  for (int m = 0; m < 4; ++m) {
    const f32x4 bv = *(const f32x4*)(cbs + wr * 64 + m * 16 + lk * 4);
#pragma unroll
    for (int r = 0; r < 4; ++r)
#pragma unroll
      for (int n = 0; n < 2; ++n) acc[m][n][r] = fmaxf(acc[m][n][r] + bv[r], 0.f);
  }
}

// ---------- fused pair layer: 512 threads, no input staging, 32KB LDS ----------
// Phase A: all 8 waves compute layer l over rows [t0-64, t0+64) -> bf16 Bu (swizzled).
// Phase B: the 4 waves owning [t0, t0+64) compute layer l+1 from Bu, f32 residual in regs.
template <int D1>
__global__ __launch_bounds__(512, 4) void layer2_k(
    const bf16* __restrict__ hbt_in, bf16* __restrict__ hbt_out,
    const bf16* __restrict__ W2, const bf16* __restrict__ cuT,
    const float* __restrict__ cb1, const float* __restrict__ db1,
    const float* __restrict__ cb2, const float* __restrict__ db2) {
  constexpr int D2 = 2 * D1;
  __shared__ uint4 Bu[128 * 16];
  char* BB = (char*)Bu;
  const int bx = blockIdx.x;
  const int tblk = ((bx & 7) << 5) | (bx >> 3);   // XCD-contiguous t ranges (256%8==0, bijective)
  const int t0 = tblk * 64, b = blockIdx.y;
  const int tid = threadIdx.x, lane = tid & 63, wid = tid >> 6;
  const int wr = wid & 1, wq = wid >> 1;
  const int lr = lane & 15, lk = lane >> 4;
  const size_t btb = (size_t)b * T;
  const bf16* Wa = W2;
  const bf16* Wb = W2 + 61440;

  // ---- phase A: layer l on 32 rows per wave ----
  const int tfA = t0 - 64 + wq * 32;
  f32x4 acc[4][2] = {};
  if (t0 >= 64 + 2 * D1) convA<D1, false>(hbt_in, btb, tfA, Wa, acc, lane, lr, lk, wr);
  else                   convA<D1, true >(hbt_in, btb, tfA, Wa, acc, lane, lr, lk, wr);
  relu_cb4(acc, cb1, wr, lk);
  cond3g(cuT, btb, tfA, Wa, acc, lane, lr, lk, wr);
  f32x4 hl[4][2];
#pragma unroll
  for (int m = 0; m < 4; ++m) {
    const int ob = wr * 64 + m * 16 + lk * 4;
    const f32x4 dv = *(const f32x4*)(db1 + ob);
#pragma unroll
    for (int n = 0; n < 2; ++n) {
      const int t = tfA + n * 16 + lr;
      bf16x4 hb = {};
      if (t >= 0) hb = *(const bf16x4*)(hbt_in + (btb + t) * 128 + ob);
      bf16x4 p;
#pragma unroll
      for (int r = 0; r < 4; ++r) {
        float vv = fmaxf(acc[m][n][r] + dv[r] + (float)hb[r], 0.f);
        if (t < 0) vv = 0.f;
        hl[m][n][r] = vv;
        p[r] = (bf16)vv;
      }
      const int rb = wq * 32 + n * 16 + lr;
      const int byteo = ob * 2;
      const int slot = byteo >> 4, wib = byteo & 15;
      *(bf16x4*)(BB + rb * 256 + (((slot ^ (rb & 7)) & 15) << 4) + wib) = p;
    }
  }
  __syncthreads();

  // ---- phase B: layer l+1 on [t0, t0+64), waves wq>=2 only (they hold f32 residual) ----
  bf16x4 po[4][2];
  if (wq >= 2) {
    const int tfB = t0 + (wq - 2) * 32;
    const int rbase = 64 + (wq - 2) * 32;
    f32x4 a2[4][2] = {};
    convL<D2>(BB, rbase, Wb, a2, lane, lr, lk, wr);
    relu_cb4(a2, cb2, wr, lk);
    cond3g(cuT, btb, tfB, Wb, a2, lane, lr, lk, wr);
#pragma unroll
    for (int m = 0; m < 4; ++m) {
      const int ob = wr * 64 + m * 16 + lk * 4;
      const f32x4 dv = *(const f32x4*)(db2 + ob);
#pragma unroll
      for (int n = 0; n < 2; ++n)
#pragma unroll
        for (int r = 0; r < 4; ++r)
          po[m][n][r] = (bf16)fmaxf(a2[m][n][r] + dv[r] + hl[m][n][r], 0.f);
    }
  }
  __syncthreads();
  if (wq >= 2) {
#pragma unroll
    for (int m = 0; m < 4; ++m) {
      const int ob = wr * 64 + m * 16 + lk * 4;
      const int byteo = ob * 2;
      const int slot = byteo >> 4, wib = byteo & 15;
#pragma unroll
      for (int n = 0; n < 2; ++n) {
        const int rb = (wq - 2) * 32 + n * 16 + lr;
        *(bf16x4*)(BB + rb * 256 + (((slot ^ (rb & 7)) & 15) << 4) + wib) = po[m][n];
      }
    }
  }
  __syncthreads();
  for (int u = tid; u < 1024; u += 512) {
    int row = u >> 4, slot = u & 15;
    uint4 v = *(const uint4*)(BB + row * 256 + (((slot ^ (row & 7)) & 15) << 4));
    *(uint4*)(hbt_out + (btb + t0 + row) * 128 + slot * 8) = v;
  }
}

// ---------- fused head: fc1 -> LDS a1 tile -> fc2 (512 threads) ----------
__global__ __launch_bounds__(512, 4) void fc12_k(
    const bf16* __restrict__ hbt, const bf16* __restrict__ fc1wb,
    const float* __restrict__ b1, const bf16* __restrict__ w2f,
    const float* __restrict__ b2, float* __restrict__ out) {
  __shared__ char A1[65536];   // 64 t-rows x 1KB (512 bf16), XOR-swizzled 16B slots
  int t0 = blockIdx.x * 64, b = blockIdx.y;
  int tid = threadIdx.x, lane = tid & 63, wid = tid >> 6;
  int lr = lane & 15, lk = lane >> 4;
  const size_t btb = (size_t)b * T;
  // fc1: 2 f-halves of 256; waves: wf = f 64-block within half, wc = t half
  int wf = wid >> 1, wc = wid & 1;
#pragma unroll
  for (int f0 = 0; f0 < 2; ++f0) {
    f32x4 acc[4][2] = {};
#pragma unroll
    for (int s = 0; s < 4; ++s) {
      bf16x8 a[4], bb[2];
#pragma unroll
      for (int m = 0; m < 4; ++m)
        a[m] = *(const bf16x8*)(fc1wb + (f0 * 256 + wf * 64 + m * 16 + lr) * 128 + s * 32 + lk * 8);
#pragma unroll
      for (int n = 0; n < 2; ++n) {
        int t = t0 + wc * 32 + n * 16 + lr;
        bb[n] = *(const bf16x8*)(hbt + (btb + t) * 128 + s * 32 + lk * 8);
      }
#pragma unroll
      for (int m = 0; m < 4; ++m)
#pragma unroll
        for (int n = 0; n < 2; ++n) acc[m][n] = MFMA_B16(a[m], bb[n], acc[m][n]);
    }
#pragma unroll
    for (int m = 0; m < 4; ++m) {
      int f = f0 * 256 + wf * 64 + m * 16 + lk * 4;
      const f32x4 bv = *(const f32x4*)(b1 + f);
#pragma unroll
      for (int n = 0; n < 2; ++n) {
        int tl = wc * 32 + n * 16 + lr;
        bf16x4 p;
#pragma unroll
        for (int r = 0; r < 4; ++r) p[r] = (bf16)fmaxf(acc[m][n][r] + bv[r], 0.f);
        int byteo = f * 2;
        int slot = (byteo >> 4) ^ (tl & 7);
        *(bf16x4*)(A1 + tl * 1024 + (slot << 4) + (byteo & 15)) = p;
      }
    }
  }
  __syncthreads();
  // fc2 from LDS: 24 padded o-tiles, 3 per wave
  f32x4 acc[4][3] = {};
#pragma unroll 4
  for (int s = 0; s < 16; ++s) {
    bf16x8 a[4], bb[3];
#pragma unroll
    for (int mt = 0; mt < 4; ++mt) {
      int tl = mt * 16 + lr;
      int slot = (s * 4 + lk) ^ (tl & 7);
      a[mt] = *(const bf16x8*)(A1 + tl * 1024 + (slot << 4));
    }
#pragma unroll
    for (int no = 0; no < 3; ++no) bb[no] = *(const bf16x8*)(w2f + ((s * 24 + wid * 3 + no) * 64 + lane) * 8);
#pragma unroll
    for (int mt = 0; mt < 4; ++mt)
#pragma unroll
      for (int no = 0; no < 3; ++no) acc[mt][no] = MFMA_B16(a[mt], bb[no], acc[mt][no]);
  }
#pragma unroll
  for (int mt = 0; mt < 4; ++mt)
#pragma unroll
    for (int no = 0; no < 3; ++no) {
      int o = (wid * 3 + no) * 16 + lr;
      if (o >= VOC) continue;
      float bias = b2[o];
#pragma unroll
      for (int r = 0; r < 4; ++r) {
        int tg = t0 + mt * 16 + lk * 4 + r;
        if (tg < T - 1) out[((size_t)b * (T - 1) + tg) * VOC + o] = acc[mt][no][r] + bias;
      }
    }
}

extern "C" void kernel_launch(void* const* d_in, const int* in_sizes, int n_in,
                              void* d_out, int out_size, void* d_ws, size_t ws_size,
                              hipStream_t stream) {
  const int*   x      = (const int*)d_in[0];
  const float* c      = (const float*)d_in[1];
  const float* emb    = (const float*)d_in[2];
  const float* enc_w  = (const float*)d_in[3];
  const float* enc_b  = (const float*)d_in[4];
  const float* conv_w = (const float*)d_in[5];
  const float* conv_b = (const float*)d_in[6];
  const float* cond_w = (const float*)d_in[7];
  const float* cond_b = (const float*)d_in[8];
  const float* fc1_w  = (const float*)d_in[9];
  const float* fc1_b  = (const float*)d_in[10];
  const float* fc2_w  = (const float*)d_in[11];
  const float* fc2_b  = (const float*)d_in[12];
  const float* ups_w  = (const float*)d_in[13];
  const float* ups_b  = (const float*)d_in[14];
  float* out = (float*)d_out;
  (void)in_sizes; (void)n_in; (void)out_size; (void)ws_size;

  char* w = (char*)d_ws;
  bf16* hbtA  = (bf16*)w;  w += 8388608;   // bf16 (b,t,128) ping
  bf16* hbtB  = (bf16*)w;  w += 8388608;   // pong
  bf16* cuT   = (bf16*)w;  w += 6291456;   // bf16 (b,t,96)
  bf16* W2    = (bf16*)w;  w += 2949120;
  bf16* fc1wb = (bf16*)w;  w += 131072;
  bf16* encwb = (bf16*)w;  w += 32768;
  bf16* embb  = (bf16*)w;  w += 66560;
  bf16* w2f   = (bf16*)w;  w += 393216;    // 24 o-tiles x 16 s x 64 lanes x 8
  float* u1   = (float*)w; w += 2621440;
  float* u2   = (float*)w; w += 655360;

  prep_wconv_k<<<dim3(2880), dim3(256), 0, stream>>>(conv_w, cond_w, W2);
  prep_misc_k<<<dim3(1218), dim3(256), 0, stream>>>(fc1_w, enc_w, emb, fc2_w, fc1wb, encwb, embb, w2f);

  ups_stage_k<<<dim3(160),  dim3(256), 0, stream>>>(c,  u1, ups_w + 0,  ups_b + 0, 64);
  ups_stage_k<<<dim3(640),  dim3(256), 0, stream>>>(u1, u2, ups_w + 12, ups_b + 1, 256);
  ups_stage_k<<<dim3(2560), dim3(256), 0, stream>>>(u2, u1, ups_w + 24, ups_b + 2, 1024);
  ups4_cuT_k<<<dim3(4096),  dim3(256), 0, stream>>>(u1, ups_w + 36, ups_b + 3, cuT);

  encode_k<<<dim3(T / 64, Bn), dim3(256), 0, stream>>>(x, embb, encwb, enc_b, hbtA);

  bf16* hti = hbtA; bf16* hto = hbtB;
  for (int p = 0; p < 12; ++p) {
    int d1 = 1 << ((2 * p) % 6);
    const bf16* wl = W2 + (size_t)p * 2 * 61440;
    const float* cb1 = conv_b + (2 * p) * 128;
    const float* db1 = cond_b + (2 * p) * 128;
    const float* cb2 = conv_b + (2 * p + 1) * 128;
    const float* db2 = cond_b + (2 * p + 1) * 128;
    dim3 g(T / 64, Bn);
    switch (d1) {
      case 1:  layer2_k<1><<<g,  dim3(512), 0, stream>>>(hti, hto, wl, cuT, cb1, db1, cb2, db2); break;
      case 4:  layer2_k<4><<<g,  dim3(512), 0, stream>>>(hti, hto, wl, cuT, cb1, db1, cb2, db2); break;
      case 16: layer2_k<16><<<g, dim3(512), 0, stream>>>(hti, hto, wl, cuT, cb1, db1, cb2, db2); break;
    }
    bf16* t1 = hti; hti = hto; hto = t1;
  }

  fc12_k<<<dim3(T / 64, Bn), dim3(512), 0, stream>>>(hti, fc1wb, fc1_b, w2f, fc2_b, out);
}

// Round 2
// 399.022 us; speedup vs baseline: 1.3997x; 1.3997x over previous
//
#include <hip/hip_runtime.h>

typedef __bf16 bf16;
typedef __attribute__((ext_vector_type(8))) __bf16 bf16x8;
typedef __attribute__((ext_vector_type(4))) __bf16 bf16x4;
typedef __attribute__((ext_vector_type(4))) float f32x4;

namespace {
constexpr int Bn = 2;
constexpr int T  = 16384;
constexpr int NL = 24;
constexpr int VOC = 259;
}

#define MFMA_B16(a, b, c) __builtin_amdgcn_mfma_f32_16x16x32_bf16((a), (b), (c), 0, 0, 0)

// ---------- prep: conv+cond weights, frag-ordered ----------
__global__ void prep_wconv_k(const float* __restrict__ cw, const float* __restrict__ dw,
                             bf16* __restrict__ W2) {
  int total = NL * 61440;
  for (int idx = blockIdx.x * 256 + threadIdx.x; idx < total; idx += gridDim.x * 256) {
    int l = idx / 61440; int r = idx % 61440;
    int s = r >> 12; int of = (r >> 9) & 7; int lane = (r >> 3) & 63; int j = r & 7;
    int o = of * 16 + (lane & 15);
    int kk = (lane >> 4) * 8 + j;
    float v;
    if (s < 12) { int k = s >> 2; int c = (s & 3) * 32 + kk; v = cw[((l * 128 + o) * 128 + c) * 3 + k]; }
    else        { int cc = (s - 12) * 32 + kk; v = (cc < 80) ? dw[(l * 128 + o) * 80 + cc] : 0.f; }
    W2[idx] = (bf16)v;
  }
}

// ---------- prep: fc1 / enc / emb bf16 copies + fc2 B-frag order (24 o-tiles) ----------
__global__ void prep_misc_k(const float* __restrict__ fc1w, const float* __restrict__ encw,
                            const float* __restrict__ emb, const float* __restrict__ fc2w,
                            bf16* __restrict__ fc1wb, bf16* __restrict__ encwb,
                            bf16* __restrict__ embb, bf16* __restrict__ w2f) {
  const int n1 = 65536, n2 = 16384, n3 = 33152, n4 = 196608;
  int total = n1 + n2 + n3 + n4;
  for (int idx = blockIdx.x * 256 + threadIdx.x; idx < total; idx += gridDim.x * 256) {
    if (idx < n1) { fc1wb[idx] = (bf16)fc1w[idx]; }
    else if (idx < n1 + n2) { int i = idx - n1; encwb[i] = (bf16)encw[i]; }
    else if (idx < n1 + n2 + n3) { int i = idx - n1 - n2; embb[i] = (bf16)emb[i]; }
    else {
      int r = idx - n1 - n2 - n3;
      int s = r / 12288; int r2 = r % 12288;
      int ot = r2 >> 9; int lane = (r2 >> 3) & 63; int j = r2 & 7;
      int o = ot * 16 + (lane & 15);
      int f = s * 32 + (lane >> 4) * 8 + j;
      w2f[r] = (bf16)((o < VOC) ? fc2w[o * 512 + f] : 0.f);
    }
  }
}

// ---------- upsample stages 1..3 (f32) ----------
__global__ void ups_stage_k(const float* __restrict__ in, float* __restrict__ out,
                            const float* __restrict__ W, const float* __restrict__ bptr, int Win) {
  int Wout = Win * 4;
  int total = Bn * 80 * Wout;
  float bias = *bptr;
  for (int idx = blockIdx.x * 256 + threadIdx.x; idx < total; idx += gridDim.x * 256) {
    int w = idx % Wout; int rest = idx / Wout;
    int hrow = rest % 80; int b = rest / 80;
    int win = w >> 2; int kw = w & 3;
    float acc = bias;
#pragma unroll
    for (int kh = 0; kh < 3; ++kh) {
      int hr = hrow + 1 - kh;
      if (hr >= 0 && hr < 80) acc += in[(b * 80 + hr) * Win + win] * W[kh * 4 + kw];
    }
    out[idx] = fmaxf(acc, 0.f);
  }
}

// ---------- fused upsample stage 4 + transpose -> cuT (b,t,96) bf16 ----------
__global__ void ups4_cuT_k(const float* __restrict__ in, const float* __restrict__ W,
                           const float* __restrict__ bptr, bf16* __restrict__ cuT) {
  int total = Bn * T * 96;
  float bias = *bptr;
  for (int idx = blockIdx.x * 256 + threadIdx.x; idx < total; idx += gridDim.x * 256) {
    int cc = idx % 96; int rest = idx / 96;
    int t = rest % T; int b = rest / T;
    float v = 0.f;
    if (cc < 80) {
      int win = t >> 2, kw = t & 3;
      float acc = bias;
#pragma unroll
      for (int kh = 0; kh < 3; ++kh) {
        int hr = cc + 1 - kh;
        if (hr >= 0 && hr < 80) acc += in[(b * 80 + hr) * 4096 + win] * W[kh * 4 + kw];
      }
      v = fmaxf(acc, 0.f);
    }
    cuT[idx] = (bf16)v;
  }
}

// ---------- encode: h = relu(enc_w @ emb[x] + enc_b) -> hbt (b,t,128) via LDS bounce ----------
__global__ __launch_bounds__(256, 2) void encode_k(
    const int* __restrict__ x, const bf16* __restrict__ embb, const bf16* __restrict__ encwb,
    const float* __restrict__ encb, bf16* __restrict__ hbt) {
  __shared__ char Eb[16384];   // 64 rows x 256B, XOR-swizzled 16B slots
  int t0 = blockIdx.x * 64, b = blockIdx.y;
  int tid = threadIdx.x, lane = tid & 63, wid = tid >> 6, wr = wid >> 1, wc = wid & 1;
  int lr = lane & 15, lk = lane >> 4;
  int tb = t0 + wc * 32;
  int xi[2];
#pragma unroll
  for (int n = 0; n < 2; ++n) xi[n] = x[b * T + tb + n * 16 + lr];
  f32x4 acc[4][2] = {};
#pragma unroll
  for (int s = 0; s < 4; ++s) {
    bf16x8 a[4], bb[2];
#pragma unroll
    for (int m = 0; m < 4; ++m) a[m] = *(const bf16x8*)(encwb + (wr * 64 + m * 16 + lr) * 128 + s * 32 + lk * 8);
#pragma unroll
    for (int n = 0; n < 2; ++n) bb[n] = *(const bf16x8*)(embb + xi[n] * 128 + s * 32 + lk * 8);
#pragma unroll
    for (int m = 0; m < 4; ++m)
#pragma unroll
      for (int n = 0; n < 2; ++n) acc[m][n] = MFMA_B16(a[m], bb[n], acc[m][n]);
  }
#pragma unroll
  for (int m = 0; m < 4; ++m)
#pragma unroll
    for (int n = 0; n < 2; ++n) {
      int obase = wr * 64 + m * 16 + lk * 4;
      int row = wc * 32 + n * 16 + lr;
      bf16x4 p;
#pragma unroll
      for (int r = 0; r < 4; ++r) p[r] = (bf16)fmaxf(acc[m][n][r] + encb[obase + r], 0.f);
      int byteo = obase * 2;
      int slot = ((byteo >> 4) ^ (row & 7)) & 15;
      *(bf16x4*)(Eb + row * 256 + (slot << 4) + (byteo & 15)) = p;
    }
  __syncthreads();
  const size_t btb = (size_t)b * T;
  for (int u = tid; u < 1024; u += 256) {
    int row = u >> 4, slot = u & 15;
    uint4 v = *(const uint4*)(Eb + row * 256 + ((((slot) ^ (row & 7)) & 15) << 4));
    *(uint4*)(hbt + (btb + t0 + row) * 128 + slot * 8) = v;
  }
}

// ---------- helpers ----------
// conv over 12 K-steps, B-fragments from XOR-swizzled LDS tile (rows of 256B).
template <int D>
__device__ __forceinline__ void convL(const char* __restrict__ L, int rowbase,
                                      const bf16* __restrict__ W,
                                      f32x4 (&acc)[4][2], int lane, int lr, int lk, int wr) {
#pragma unroll
  for (int s = 0; s < 12; ++s) {
    const int k = s >> 2, shift = (k - 2) * D, sb = (s & 3) * 4;
    bf16x8 a[4], bb[2];
#pragma unroll
    for (int m = 0; m < 4; ++m) a[m] = *(const bf16x8*)(W + ((s * 8 + wr * 4 + m) * 64 + lane) * 8);
#pragma unroll
    for (int n = 0; n < 2; ++n) {
      int row = rowbase + n * 16 + lr + shift;
      int slot = ((sb + lk) ^ (row & 7)) & 15;
      bb[n] = *(const bf16x8*)(L + row * 256 + slot * 16);
    }
#pragma unroll
    for (int m = 0; m < 4; ++m)
#pragma unroll
      for (int n = 0; n < 2; ++n) acc[m][n] = MFMA_B16(a[m], bb[n], acc[m][n]);
  }
}

__device__ __forceinline__ void cond3g(const bf16* __restrict__ cuT, size_t btb, int tfirst,
                                       const bf16* __restrict__ W,
                                       f32x4 (&acc)[4][2], int lane, int lr, int lk, int wr) {
#pragma unroll
  for (int s = 12; s < 15; ++s) {
    bf16x8 a[4], bb[2];
#pragma unroll
    for (int m = 0; m < 4; ++m) a[m] = *(const bf16x8*)(W + ((s * 8 + wr * 4 + m) * 64 + lane) * 8);
#pragma unroll
    for (int n = 0; n < 2; ++n) {
      int t = tfirst + n * 16 + lr;
      if (t < 0) t = 0;
      bb[n] = *(const bf16x8*)(cuT + (btb + t) * 96 + (s - 12) * 32 + lk * 8);
    }
#pragma unroll
    for (int m = 0; m < 4; ++m)
#pragma unroll
      for (int n = 0; n < 2; ++n) acc[m][n] = MFMA_B16(a[m], bb[n], acc[m][n]);
  }
}

__device__ __forceinline__ void relu_cb4(f32x4 (&acc)[4][2], const float* __restrict__ cbs,
                                         int wr, int lk) {
#pragma unroll
  for (int m = 0; m < 4; ++m) {
    const f32x4 bv = *(const f32x4*)(cbs + wr * 64 + m * 16 + lk * 4);
#pragma unroll
    for (int r = 0; r < 4; ++r)
#pragma unroll
      for (int n = 0; n < 2; ++n) acc[m][n][r] = fmaxf(acc[m][n][r] + bv[r], 0.f);
  }
}

// ---------- fused pair layer: 512 threads, staged LDS input, 8-wave phase A ----------
// Stage Au = hbt rows [t0-64-AOFF, t0+64) coalesced.
// Phase A: 8 waves compute layer l over [t0-64, t0+64) from Au -> bf16 Bu (swizzled).
// Phase B: 4 waves (rows [t0, t0+64)) compute layer l+1 from Bu, f32 residual in regs.
template <int D1>
__global__ __launch_bounds__(512, 4) void layer2_k(
    const bf16* __restrict__ hbt_in, bf16* __restrict__ hbt_out,
    const bf16* __restrict__ W2, const bf16* __restrict__ cuT,
    const float* __restrict__ cb1, const float* __restrict__ db1,
    const float* __restrict__ cb2, const float* __restrict__ db2) {
  constexpr int D2 = 2 * D1;
  constexpr int AOFF = (D1 == 16) ? 32 : 8;
  constexpr int AR = 128 + AOFF;
  __shared__ uint4 Au[AR * 16];
  __shared__ uint4 Bu[128 * 16];
  char* AB = (char*)Au;
  char* BB = (char*)Bu;
  const int bx = blockIdx.x;
  const int tblk = ((bx & 7) << 5) | (bx >> 3);   // XCD-contiguous t ranges (256%8==0, bijective)
  const int t0 = tblk * 64, b = blockIdx.y;
  const int tid = threadIdx.x, lane = tid & 63, wid = tid >> 6;
  const int wr = wid & 1, wq = wid >> 1;
  const int lr = lane & 15, lk = lane >> 4;
  const size_t btb = (size_t)b * T;
  const bf16* Wa = W2;
  const bf16* Wb = W2 + 61440;

  // ---- stage Au: rows [t0-64-AOFF, t0+64), coalesced uint4, XOR-swizzled ----
  uint4 zv; zv.x = zv.y = zv.z = zv.w = 0;
  for (int u = tid; u < AR * 16; u += 512) {
    int row = u >> 4, slot = u & 15;
    int t = t0 - 64 - AOFF + row;
    uint4 v = (t >= 0) ? *(const uint4*)(hbt_in + (btb + t) * 128 + slot * 8) : zv;
    *(uint4*)(AB + row * 256 + (((slot ^ (row & 7)) & 15) << 4)) = v;
  }
  __syncthreads();

  // ---- phase A: layer l on 32 rows per wave, from Au ----
  const int tfA = t0 - 64 + wq * 32;
  const int rbA = AOFF + wq * 32;
  f32x4 acc[4][2] = {};
  convL<D1>(AB, rbA, Wa, acc, lane, lr, lk, wr);
  relu_cb4(acc, cb1, wr, lk);
  cond3g(cuT, btb, tfA, Wa, acc, lane, lr, lk, wr);
  f32x4 hl[4][2];
#pragma unroll
  for (int m = 0; m < 4; ++m) {
    const int ob = wr * 64 + m * 16 + lk * 4;
    const f32x4 dv = *(const f32x4*)(db1 + ob);
    const int byteo = ob * 2;
#pragma unroll
    for (int n = 0; n < 2; ++n) {
      const int t = tfA + n * 16 + lr;
      const int rowA = rbA + n * 16 + lr;
      const int slotA = ((byteo >> 4) ^ (rowA & 7)) & 15;
      bf16x4 hb = *(const bf16x4*)(AB + rowA * 256 + (slotA << 4) + (byteo & 15));
      bf16x4 p;
#pragma unroll
      for (int r = 0; r < 4; ++r) {
        float vv = fmaxf(acc[m][n][r] + dv[r] + (float)hb[r], 0.f);
        if (t < 0) vv = 0.f;
        hl[m][n][r] = vv;
        p[r] = (bf16)vv;
      }
      const int rb = wq * 32 + n * 16 + lr;
      const int slot = byteo >> 4, wib = byteo & 15;
      *(bf16x4*)(BB + rb * 256 + (((slot ^ (rb & 7)) & 15) << 4) + wib) = p;
    }
  }
  __syncthreads();

  // ---- phase B: layer l+1 on [t0, t0+64), waves wq>=2 only (they hold f32 residual) ----
  bf16x4 po[4][2];
  if (wq >= 2) {
    const int tfB = t0 + (wq - 2) * 32;
    const int rbase = 64 + (wq - 2) * 32;
    f32x4 a2[4][2] = {};
    convL<D2>(BB, rbase, Wb, a2, lane, lr, lk, wr);
    relu_cb4(a2, cb2, wr, lk);
    cond3g(cuT, btb, tfB, Wb, a2, lane, lr, lk, wr);
#pragma unroll
    for (int m = 0; m < 4; ++m) {
      const int ob = wr * 64 + m * 16 + lk * 4;
      const f32x4 dv = *(const f32x4*)(db2 + ob);
#pragma unroll
      for (int n = 0; n < 2; ++n)
#pragma unroll
        for (int r = 0; r < 4; ++r)
          po[m][n][r] = (bf16)fmaxf(a2[m][n][r] + dv[r] + hl[m][n][r], 0.f);
    }
  }
  __syncthreads();
  if (wq >= 2) {
#pragma unroll
    for (int m = 0; m < 4; ++m) {
      const int ob = wr * 64 + m * 16 + lk * 4;
      const int byteo = ob * 2;
      const int slot = byteo >> 4, wib = byteo & 15;
#pragma unroll
      for (int n = 0; n < 2; ++n) {
        const int rb = (wq - 2) * 32 + n * 16 + lr;
        *(bf16x4*)(BB + rb * 256 + (((slot ^ (rb & 7)) & 15) << 4) + wib) = po[m][n];
      }
    }
  }
  __syncthreads();
  for (int u = tid; u < 1024; u += 512) {
    int row = u >> 4, slot = u & 15;
    uint4 v = *(const uint4*)(BB + row * 256 + (((slot ^ (row & 7)) & 15) << 4));
    *(uint4*)(hbt_out + (btb + t0 + row) * 128 + slot * 8) = v;
  }
}

// ---------- fused head: fc1 -> LDS a1 tile -> fc2 (512 threads) ----------
__global__ __launch_bounds__(512, 4) void fc12_k(
    const bf16* __restrict__ hbt, const bf16* __restrict__ fc1wb,
    const float* __restrict__ b1, const bf16* __restrict__ w2f,
    const float* __restrict__ b2, float* __restrict__ out) {
  __shared__ char A1[65536];   // 64 t-rows x 1KB (512 bf16), XOR-swizzled 16B slots
  int t0 = blockIdx.x * 64, b = blockIdx.y;
  int tid = threadIdx.x, lane = tid & 63, wid = tid >> 6;
  int lr = lane & 15, lk = lane >> 4;
  const size_t btb = (size_t)b * T;
  // fc1: 2 f-halves of 256; waves: wf = f 64-block within half, wc = t half
  int wf = wid >> 1, wc = wid & 1;
#pragma unroll
  for (int f0 = 0; f0 < 2; ++f0) {
    f32x4 acc[4][2] = {};
#pragma unroll
    for (int s = 0; s < 4; ++s) {
      bf16x8 a[4], bb[2];
#pragma unroll
      for (int m = 0; m < 4; ++m)
        a[m] = *(const bf16x8*)(fc1wb + (f0 * 256 + wf * 64 + m * 16 + lr) * 128 + s * 32 + lk * 8);
#pragma unroll
      for (int n = 0; n < 2; ++n) {
        int t = t0 + wc * 32 + n * 16 + lr;
        bb[n] = *(const bf16x8*)(hbt + (btb + t) * 128 + s * 32 + lk * 8);
      }
#pragma unroll
      for (int m = 0; m < 4; ++m)
#pragma unroll
        for (int n = 0; n < 2; ++n) acc[m][n] = MFMA_B16(a[m], bb[n], acc[m][n]);
    }
#pragma unroll
    for (int m = 0; m < 4; ++m) {
      int f = f0 * 256 + wf * 64 + m * 16 + lk * 4;
      const f32x4 bv = *(const f32x4*)(b1 + f);
#pragma unroll
      for (int n = 0; n < 2; ++n) {
        int tl = wc * 32 + n * 16 + lr;
        bf16x4 p;
#pragma unroll
        for (int r = 0; r < 4; ++r) p[r] = (bf16)fmaxf(acc[m][n][r] + bv[r], 0.f);
        int byteo = f * 2;
        int slot = (byteo >> 4) ^ (tl & 7);
        *(bf16x4*)(A1 + tl * 1024 + (slot << 4) + (byteo & 15)) = p;
      }
    }
  }
  __syncthreads();
  // fc2 from LDS: 24 padded o-tiles, 3 per wave
  f32x4 acc[4][3] = {};
#pragma unroll 4
  for (int s = 0; s < 16; ++s) {
    bf16x8 a[4], bb[3];
#pragma unroll
    for (int mt = 0; mt < 4; ++mt) {
      int tl = mt * 16 + lr;
      int slot = (s * 4 + lk) ^ (tl & 7);
      a[mt] = *(const bf16x8*)(A1 + tl * 1024 + (slot << 4));
    }
#pragma unroll
    for (int no = 0; no < 3; ++no) bb[no] = *(const bf16x8*)(w2f + ((s * 24 + wid * 3 + no) * 64 + lane) * 8);
#pragma unroll
    for (int mt = 0; mt < 4; ++mt)
#pragma unroll
      for (int no = 0; no < 3; ++no) acc[mt][no] = MFMA_B16(a[mt], bb[no], acc[mt][no]);
  }
#pragma unroll
  for (int mt = 0; mt < 4; ++mt)
#pragma unroll
    for (int no = 0; no < 3; ++no) {
      int o = (wid * 3 + no) * 16 + lr;
      if (o >= VOC) continue;
      float bias = b2[o];
#pragma unroll
      for (int r = 0; r < 4; ++r) {
        int tg = t0 + mt * 16 + lk * 4 + r;
        if (tg < T - 1) out[((size_t)b * (T - 1) + tg) * VOC + o] = acc[mt][no][r] + bias;
      }
    }
}

extern "C" void kernel_launch(void* const* d_in, const int* in_sizes, int n_in,
                              void* d_out, int out_size, void* d_ws, size_t ws_size,
                              hipStream_t stream) {
  const int*   x      = (const int*)d_in[0];
  const float* c      = (const float*)d_in[1];
  const float* emb    = (const float*)d_in[2];
  const float* enc_w  = (const float*)d_in[3];
  const float* enc_b  = (const float*)d_in[4];
  const float* conv_w = (const float*)d_in[5];
  const float* conv_b = (const float*)d_in[6];
  const float* cond_w = (const float*)d_in[7];
  const float* cond_b = (const float*)d_in[8];
  const float* fc1_w  = (const float*)d_in[9];
  const float* fc1_b  = (const float*)d_in[10];
  const float* fc2_w  = (const float*)d_in[11];
  const float* fc2_b  = (const float*)d_in[12];
  const float* ups_w  = (const float*)d_in[13];
  const float* ups_b  = (const float*)d_in[14];
  float* out = (float*)d_out;
  (void)in_sizes; (void)n_in; (void)out_size; (void)ws_size;

  char* w = (char*)d_ws;
  bf16* hbtA  = (bf16*)w;  w += 8388608;   // bf16 (b,t,128) ping
  bf16* hbtB  = (bf16*)w;  w += 8388608;   // pong
  bf16* cuT   = (bf16*)w;  w += 6291456;   // bf16 (b,t,96)
  bf16* W2    = (bf16*)w;  w += 2949120;
  bf16* fc1wb = (bf16*)w;  w += 131072;
  bf16* encwb = (bf16*)w;  w += 32768;
  bf16* embb  = (bf16*)w;  w += 66560;
  bf16* w2f   = (bf16*)w;  w += 393216;    // 24 o-tiles x 16 s x 64 lanes x 8
  float* u1   = (float*)w; w += 2621440;
  float* u2   = (float*)w; w += 655360;

  prep_wconv_k<<<dim3(2880), dim3(256), 0, stream>>>(conv_w, cond_w, W2);
  prep_misc_k<<<dim3(1218), dim3(256), 0, stream>>>(fc1_w, enc_w, emb, fc2_w, fc1wb, encwb, embb, w2f);

  ups_stage_k<<<dim3(160),  dim3(256), 0, stream>>>(c,  u1, ups_w + 0,  ups_b + 0, 64);
  ups_stage_k<<<dim3(640),  dim3(256), 0, stream>>>(u1, u2, ups_w + 12, ups_b + 1, 256);
  ups_stage_k<<<dim3(2560), dim3(256), 0, stream>>>(u2, u1, ups_w + 24, ups_b + 2, 1024);
  ups4_cuT_k<<<dim3(4096),  dim3(256), 0, stream>>>(u1, ups_w + 36, ups_b + 3, cuT);

  encode_k<<<dim3(T / 64, Bn), dim3(256), 0, stream>>>(x, embb, encwb, enc_b, hbtA);

  bf16* hti = hbtA; bf16* hto = hbtB;
  for (int p = 0; p < 12; ++p) {
    int d1 = 1 << ((2 * p) % 6);
    const bf16* wl = W2 + (size_t)p * 2 * 61440;
    const float* cb1 = conv_b + (2 * p) * 128;
    const float* db1 = cond_b + (2 * p) * 128;
    const float* cb2 = conv_b + (2 * p + 1) * 128;
    const float* db2 = cond_b + (2 * p + 1) * 128;
    dim3 g(T / 64, Bn);
    switch (d1) {
      case 1:  layer2_k<1><<<g,  dim3(512), 0, stream>>>(hti, hto, wl, cuT, cb1, db1, cb2, db2); break;
      case 4:  layer2_k<4><<<g,  dim3(512), 0, stream>>>(hti, hto, wl, cuT, cb1, db1, cb2, db2); break;
      case 16: layer2_k<16><<<g, dim3(512), 0, stream>>>(hti, hto, wl, cuT, cb1, db1, cb2, db2); break;
    }
    bf16* t1 = hti; hti = hto; hto = t1;
  }

  fc12_k<<<dim3(T / 64, Bn), dim3(512), 0, stream>>>(hti, fc1wb, fc1_b, w2f, fc2_b, out);
}

// Round 3
// 361.043 us; speedup vs baseline: 1.5469x; 1.1052x over previous
//
#include <hip/hip_runtime.h>

typedef __bf16 bf16;
typedef __attribute__((ext_vector_type(8))) __bf16 bf16x8;
typedef __attribute__((ext_vector_type(4))) __bf16 bf16x4;
typedef __attribute__((ext_vector_type(4))) float f32x4;

namespace {
constexpr int Bn = 2;
constexpr int T  = 16384;
constexpr int NL = 24;
constexpr int VOC = 259;
}

#define MFMA_B16(a, b, c) __builtin_amdgcn_mfma_f32_16x16x32_bf16((a), (b), (c), 0, 0, 0)

// ---------- prep: conv+cond weights, frag-ordered ----------
__global__ void prep_wconv_k(const float* __restrict__ cw, const float* __restrict__ dw,
                             bf16* __restrict__ W2) {
  int total = NL * 61440;
  for (int idx = blockIdx.x * 256 + threadIdx.x; idx < total; idx += gridDim.x * 256) {
    int l = idx / 61440; int r = idx % 61440;
    int s = r >> 12; int of = (r >> 9) & 7; int lane = (r >> 3) & 63; int j = r & 7;
    int o = of * 16 + (lane & 15);
    int kk = (lane >> 4) * 8 + j;
    float v;
    if (s < 12) { int k = s >> 2; int c = (s & 3) * 32 + kk; v = cw[((l * 128 + o) * 128 + c) * 3 + k]; }
    else        { int cc = (s - 12) * 32 + kk; v = (cc < 80) ? dw[(l * 128 + o) * 80 + cc] : 0.f; }
    W2[idx] = (bf16)v;
  }
}

// ---------- prep: fc1 / enc / emb bf16 copies + fc2 B-frag order (24 o-tiles) ----------
__global__ void prep_misc_k(const float* __restrict__ fc1w, const float* __restrict__ encw,
                            const float* __restrict__ emb, const float* __restrict__ fc2w,
                            bf16* __restrict__ fc1wb, bf16* __restrict__ encwb,
                            bf16* __restrict__ embb, bf16* __restrict__ w2f) {
  const int n1 = 65536, n2 = 16384, n3 = 33152, n4 = 196608;
  int total = n1 + n2 + n3 + n4;
  for (int idx = blockIdx.x * 256 + threadIdx.x; idx < total; idx += gridDim.x * 256) {
    if (idx < n1) { fc1wb[idx] = (bf16)fc1w[idx]; }
    else if (idx < n1 + n2) { int i = idx - n1; encwb[i] = (bf16)encw[i]; }
    else if (idx < n1 + n2 + n3) { int i = idx - n1 - n2; embb[i] = (bf16)emb[i]; }
    else {
      int r = idx - n1 - n2 - n3;
      int s = r / 12288; int r2 = r % 12288;
      int ot = r2 >> 9; int lane = (r2 >> 3) & 63; int j = r2 & 7;
      int o = ot * 16 + (lane & 15);
      int f = s * 32 + (lane >> 4) * 8 + j;
      w2f[r] = (bf16)((o < VOC) ? fc2w[o * 512 + f] : 0.f);
    }
  }
}

// ---------- upsample stages 1..3 (f32) ----------
__global__ void ups_stage_k(const float* __restrict__ in, float* __restrict__ out,
                            const float* __restrict__ W, const float* __restrict__ bptr, int Win) {
  int Wout = Win * 4;
  int total = Bn * 80 * Wout;
  float bias = *bptr;
  for (int idx = blockIdx.x * 256 + threadIdx.x; idx < total; idx += gridDim.x * 256) {
    int w = idx % Wout; int rest = idx / Wout;
    int hrow = rest % 80; int b = rest / 80;
    int win = w >> 2; int kw = w & 3;
    float acc = bias;
#pragma unroll
    for (int kh = 0; kh < 3; ++kh) {
      int hr = hrow + 1 - kh;
      if (hr >= 0 && hr < 80) acc += in[(b * 80 + hr) * Win + win] * W[kh * 4 + kw];
    }
    out[idx] = fmaxf(acc, 0.f);
  }
}

// ---------- fused upsample stage 4 -> cuT2 in B-frag tiled layout ----------
// cuT2[((b*1024 + t/16)*3 + cc/32)*512 + lane*8 + j], lane = (cc%32/8)*16 + (t%16)
__global__ void ups4_cuT_k(const float* __restrict__ in, const float* __restrict__ W,
                           const float* __restrict__ bptr, bf16* __restrict__ cuT2) {
  int total = Bn * 1024 * 3 * 512;
  float bias = *bptr;
  for (int idx = blockIdx.x * 256 + threadIdx.x; idx < total; idx += gridDim.x * 256) {
    int low = idx & 511; int j = low & 7; int lane = low >> 3;
    int g = idx >> 9; int sc = g % 3; int gt = g / 3; int tile = gt & 1023; int b = gt >> 10;
    int lr = lane & 15, lk = lane >> 4;
    int t = tile * 16 + lr;
    int cc = sc * 32 + lk * 8 + j;
    float v = 0.f;
    if (cc < 80) {
      int win = t >> 2, kw = t & 3;
      float acc = bias;
#pragma unroll
      for (int kh = 0; kh < 3; ++kh) {
        int hr = cc + 1 - kh;
        if (hr >= 0 && hr < 80) acc += in[(b * 80 + hr) * 4096 + win] * W[kh * 4 + kw];
      }
      v = fmaxf(acc, 0.f);
    }
    cuT2[idx] = (bf16)v;
  }
}

// ---------- encode: h = relu(enc_w @ emb[x] + enc_b) -> hbt (b,t,128) via LDS bounce ----------
__global__ __launch_bounds__(256, 2) void encode_k(
    const int* __restrict__ x, const bf16* __restrict__ embb, const bf16* __restrict__ encwb,
    const float* __restrict__ encb, bf16* __restrict__ hbt) {
  __shared__ char Eb[16384];   // 64 rows x 256B, XOR-swizzled 16B slots
  int t0 = blockIdx.x * 64, b = blockIdx.y;
  int tid = threadIdx.x, lane = tid & 63, wid = tid >> 6, wr = wid >> 1, wc = wid & 1;
  int lr = lane & 15, lk = lane >> 4;
  int tb = t0 + wc * 32;
  int xi[2];
#pragma unroll
  for (int n = 0; n < 2; ++n) xi[n] = x[b * T + tb + n * 16 + lr];
  f32x4 acc[4][2] = {};
#pragma unroll
  for (int s = 0; s < 4; ++s) {
    bf16x8 a[4], bb[2];
#pragma unroll
    for (int m = 0; m < 4; ++m) a[m] = *(const bf16x8*)(encwb + (wr * 64 + m * 16 + lr) * 128 + s * 32 + lk * 8);
#pragma unroll
    for (int n = 0; n < 2; ++n) bb[n] = *(const bf16x8*)(embb + xi[n] * 128 + s * 32 + lk * 8);
#pragma unroll
    for (int m = 0; m < 4; ++m)
#pragma unroll
      for (int n = 0; n < 2; ++n) acc[m][n] = MFMA_B16(a[m], bb[n], acc[m][n]);
  }
#pragma unroll
  for (int m = 0; m < 4; ++m)
#pragma unroll
    for (int n = 0; n < 2; ++n) {
      int obase = wr * 64 + m * 16 + lk * 4;
      int row = wc * 32 + n * 16 + lr;
      bf16x4 p;
#pragma unroll
      for (int r = 0; r < 4; ++r) p[r] = (bf16)fmaxf(acc[m][n][r] + encb[obase + r], 0.f);
      int byteo = obase * 2;
      int slot = ((byteo >> 4) ^ (row & 7)) & 15;
      *(bf16x4*)(Eb + row * 256 + (slot << 4) + (byteo & 15)) = p;
    }
  __syncthreads();
  const size_t btb = (size_t)b * T;
  for (int u = tid; u < 1024; u += 256) {
    int row = u >> 4, slot = u & 15;
    uint4 v = *(const uint4*)(Eb + row * 256 + ((((slot) ^ (row & 7)) & 15) << 4));
    *(uint4*)(hbt + (btb + t0 + row) * 128 + slot * 8) = v;
  }
}

// ---------- helpers ----------
// conv over 12 K-steps, B-fragments from XOR-swizzled LDS tile (rows of 256B).
// Frag n covers rows rowbase + n*NSTR + [0,16).
template <int D, int NN, int NSTR>
__device__ __forceinline__ void convL(const char* __restrict__ L, int rowbase,
                                      const bf16* __restrict__ W,
                                      f32x4 (&acc)[4][NN], int lane, int lr, int lk, int wr) {
#pragma unroll
  for (int s = 0; s < 12; ++s) {
    const int k = s >> 2, shift = (k - 2) * D, sb = (s & 3) * 4;
    bf16x8 a[4], bb[NN];
#pragma unroll
    for (int m = 0; m < 4; ++m) a[m] = *(const bf16x8*)(W + ((s * 8 + wr * 4 + m) * 64 + lane) * 8);
#pragma unroll
    for (int n = 0; n < NN; ++n) {
      int row = rowbase + n * NSTR + lr + shift;
      int slot = ((sb + lk) ^ (row & 7)) & 15;
      bb[n] = *(const bf16x8*)(L + row * 256 + slot * 16);
    }
#pragma unroll
    for (int m = 0; m < 4; ++m)
#pragma unroll
      for (int n = 0; n < NN; ++n) acc[m][n] = MFMA_B16(a[m], bb[n], acc[m][n]);
  }
}

// cond: B-frags contiguous from frag-tiled cuT2. Frag n covers 16-aligned rows tfirst + n*64.
template <int NN>
__device__ __forceinline__ void cond3t(const bf16* __restrict__ cuT2, size_t bt16, int tfirst,
                                       const bf16* __restrict__ W,
                                       f32x4 (&acc)[4][NN], int lane, int wr) {
#pragma unroll
  for (int s = 12; s < 15; ++s) {
    bf16x8 a[4], bb[NN];
#pragma unroll
    for (int m = 0; m < 4; ++m) a[m] = *(const bf16x8*)(W + ((s * 8 + wr * 4 + m) * 64 + lane) * 8);
#pragma unroll
    for (int n = 0; n < NN; ++n) {
      int tt = tfirst + n * 64;
      if (tt < 0) tt = 0;
      int tile = tt >> 4;
      bb[n] = *(const bf16x8*)(cuT2 + ((bt16 + tile) * 3 + (s - 12)) * 512 + lane * 8);
    }
#pragma unroll
    for (int m = 0; m < 4; ++m)
#pragma unroll
      for (int n = 0; n < NN; ++n) acc[m][n] = MFMA_B16(a[m], bb[n], acc[m][n]);
  }
}

template <int NN>
__device__ __forceinline__ void relu_cb(f32x4 (&acc)[4][NN], const float* __restrict__ cbs,
                                        int wr, int lk) {
#pragma unroll
  for (int m = 0; m < 4; ++m) {
    const f32x4 bv = *(const f32x4*)(cbs + wr * 64 + m * 16 + lk * 4);
#pragma unroll
    for (int r = 0; r < 4; ++r)
#pragma unroll
      for (int n = 0; n < NN; ++n) acc[m][n][r] = fmaxf(acc[m][n][r] + bv[r], 0.f);
  }
}

// ---------- fused pair layer: 512 threads, staged LDS input, all-wave phases ----------
// Phase A: 8 waves, frag n=0 -> rows [t0-64+wq*16), n=1 -> rows [t0+wq*16) (16 rows each).
// Phase B: 8 waves, NN=1, rows [t0+wq*16); every wave holds its f32 residual from phase A.
template <int D1>
__global__ __launch_bounds__(512, 4) void layer2_k(
    const bf16* __restrict__ hbt_in, bf16* __restrict__ hbt_out,
    const bf16* __restrict__ W2, const bf16* __restrict__ cuT2,
    const float* __restrict__ cb1, const float* __restrict__ db1,
    const float* __restrict__ cb2, const float* __restrict__ db2) {
  constexpr int D2 = 2 * D1;
  constexpr int AOFF = (D1 == 16) ? 32 : 8;
  constexpr int AR = 128 + AOFF;
  __shared__ uint4 Au[AR * 16];
  __shared__ uint4 Bu[128 * 16];
  char* AB = (char*)Au;
  char* BB = (char*)Bu;
  const int bx = blockIdx.x;
  const int tblk = ((bx & 7) << 5) | (bx >> 3);   // XCD-contiguous t ranges (256%8==0, bijective)
  const int t0 = tblk * 64, b = blockIdx.y;
  const int tid = threadIdx.x, lane = tid & 63, wid = tid >> 6;
  const int wr = wid & 1, wq = wid >> 1;
  const int lr = lane & 15, lk = lane >> 4;
  const size_t btb = (size_t)b * T;
  const size_t bt16 = (size_t)b * 1024;
  const bf16* Wa = W2;
  const bf16* Wb = W2 + 61440;

  // ---- stage Au: rows [t0-64-AOFF, t0+64), coalesced uint4, XOR-swizzled ----
  uint4 zv; zv.x = zv.y = zv.z = zv.w = 0;
  for (int u = tid; u < AR * 16; u += 512) {
    int row = u >> 4, slot = u & 15;
    int t = t0 - 64 - AOFF + row;
    uint4 v = (t >= 0) ? *(const uint4*)(hbt_in + (btb + t) * 128 + slot * 8) : zv;
    *(uint4*)(AB + row * 256 + (((slot ^ (row & 7)) & 15) << 4)) = v;
  }
  __syncthreads();

  // ---- phase A: layer l, 2 frags of 16 rows per wave ----
  const int tfA = t0 - 64 + wq * 16;
  const int rbA = AOFF + wq * 16;
  f32x4 acc[4][2] = {};
  convL<D1, 2, 64>(AB, rbA, Wa, acc, lane, lr, lk, wr);
  relu_cb<2>(acc, cb1, wr, lk);
  cond3t<2>(cuT2, bt16, tfA, Wa, acc, lane, wr);
  f32x4 hl[4];   // f32 residual for n=1 rows (phase B input rows)
#pragma unroll
  for (int m = 0; m < 4; ++m) {
    const int ob = wr * 64 + m * 16 + lk * 4;
    const f32x4 dv = *(const f32x4*)(db1 + ob);
    const int byteo = ob * 2;
#pragma unroll
    for (int n = 0; n < 2; ++n) {
      const int t = tfA + n * 64 + lr;
      const int rowA = rbA + n * 64 + lr;
      const int slotA = ((byteo >> 4) ^ (rowA & 7)) & 15;
      bf16x4 hb = *(const bf16x4*)(AB + rowA * 256 + (slotA << 4) + (byteo & 15));
      bf16x4 p;
#pragma unroll
      for (int r = 0; r < 4; ++r) {
        float vv = fmaxf(acc[m][n][r] + dv[r] + (float)hb[r], 0.f);
        if (t < 0) vv = 0.f;
        if (n == 1) hl[m][r] = vv;
        p[r] = (bf16)vv;
      }
      const int rb = wq * 16 + n * 64 + lr;
      const int slot = byteo >> 4, wib = byteo & 15;
      *(bf16x4*)(BB + rb * 256 + (((slot ^ (rb & 7)) & 15) << 4) + wib) = p;
    }
  }
  __syncthreads();

  // ---- phase B: layer l+1, all 8 waves, 16 rows each ----
  const int tfB = t0 + wq * 16;
  const int rbase = 64 + wq * 16;
  f32x4 a2[4][1] = {};
  convL<D2, 1, 64>(BB, rbase, Wb, a2, lane, lr, lk, wr);
  relu_cb<1>(a2, cb2, wr, lk);
  cond3t<1>(cuT2, bt16, tfB, Wb, a2, lane, wr);
  bf16x4 po[4];
#pragma unroll
  for (int m = 0; m < 4; ++m) {
    const int ob = wr * 64 + m * 16 + lk * 4;
    const f32x4 dv = *(const f32x4*)(db2 + ob);
#pragma unroll
    for (int r = 0; r < 4; ++r)
      po[m][r] = (bf16)fmaxf(a2[m][0][r] + dv[r] + hl[m][r], 0.f);
  }
  __syncthreads();
#pragma unroll
  for (int m = 0; m < 4; ++m) {
    const int ob = wr * 64 + m * 16 + lk * 4;
    const int byteo = ob * 2;
    const int slot = byteo >> 4, wib = byteo & 15;
    const int rb = wq * 16 + lr;
    *(bf16x4*)(BB + rb * 256 + (((slot ^ (rb & 7)) & 15) << 4) + wib) = po[m];
  }
  __syncthreads();
  for (int u = tid; u < 1024; u += 512) {
    int row = u >> 4, slot = u & 15;
    uint4 v = *(const uint4*)(BB + row * 256 + (((slot ^ (row & 7)) & 15) << 4));
    *(uint4*)(hbt_out + (btb + t0 + row) * 128 + slot * 8) = v;
  }
}

// ---------- fused head: fc1 (LDS-staged input) -> LDS a1 tile -> fc2 (512 threads) ----------
__global__ __launch_bounds__(512, 4) void fc12_k(
    const bf16* __restrict__ hbt, const bf16* __restrict__ fc1wb,
    const float* __restrict__ b1, const bf16* __restrict__ w2f,
    const float* __restrict__ b2, float* __restrict__ out) {
  __shared__ char A1[65536];   // 64 t-rows x 1KB (512 bf16), XOR-swizzled 16B slots
  __shared__ char H[16384];    // 64 t-rows x 256B, XOR-swizzled 16B slots
  int t0 = blockIdx.x * 64, b = blockIdx.y;
  int tid = threadIdx.x, lane = tid & 63, wid = tid >> 6;
  int lr = lane & 15, lk = lane >> 4;
  const size_t btb = (size_t)b * T;
  // stage H tile (coalesced)
  for (int u = tid; u < 1024; u += 512) {
    int row = u >> 4, slot = u & 15;
    uint4 v = *(const uint4*)(hbt + (btb + t0 + row) * 128 + slot * 8);
    *(uint4*)(H + row * 256 + (((slot ^ (row & 7)) & 15) << 4)) = v;
  }
  __syncthreads();
  // fc1: 2 f-halves of 256; waves: wf = f 64-block within half, wc = t half
  int wf = wid >> 1, wc = wid & 1;
#pragma unroll
  for (int f0 = 0; f0 < 2; ++f0) {
    f32x4 acc[4][2] = {};
#pragma unroll
    for (int s = 0; s < 4; ++s) {
      bf16x8 a[4], bb[2];
#pragma unroll
      for (int m = 0; m < 4; ++m)
        a[m] = *(const bf16x8*)(fc1wb + (f0 * 256 + wf * 64 + m * 16 + lr) * 128 + s * 32 + lk * 8);
#pragma unroll
      for (int n = 0; n < 2; ++n) {
        int row = wc * 32 + n * 16 + lr;
        int slot = ((s * 4 + lk) ^ (row & 7)) & 15;
        bb[n] = *(const bf16x8*)(H + row * 256 + slot * 16);
      }
#pragma unroll
      for (int m = 0; m < 4; ++m)
#pragma unroll
        for (int n = 0; n < 2; ++n) acc[m][n] = MFMA_B16(a[m], bb[n], acc[m][n]);
    }
#pragma unroll
    for (int m = 0; m < 4; ++m) {
      int f = f0 * 256 + wf * 64 + m * 16 + lk * 4;
      const f32x4 bv = *(const f32x4*)(b1 + f);
#pragma unroll
      for (int n = 0; n < 2; ++n) {
        int tl = wc * 32 + n * 16 + lr;
        bf16x4 p;
#pragma unroll
        for (int r = 0; r < 4; ++r) p[r] = (bf16)fmaxf(acc[m][n][r] + bv[r], 0.f);
        int byteo = f * 2;
        int slot = (byteo >> 4) ^ (tl & 7);
        *(bf16x4*)(A1 + tl * 1024 + (slot << 4) + (byteo & 15)) = p;
      }
    }
  }
  __syncthreads();
  // fc2 from LDS: 24 padded o-tiles, 3 per wave
  f32x4 acc[4][3] = {};
#pragma unroll 4
  for (int s = 0; s < 16; ++s) {
    bf16x8 a[4], bb[3];
#pragma unroll
    for (int mt = 0; mt < 4; ++mt) {
      int tl = mt * 16 + lr;
      int slot = (s * 4 + lk) ^ (tl & 7);
      a[mt] = *(const bf16x8*)(A1 + tl * 1024 + (slot << 4));
    }
#pragma unroll
    for (int no = 0; no < 3; ++no) bb[no] = *(const bf16x8*)(w2f + ((s * 24 + wid * 3 + no) * 64 + lane) * 8);
#pragma unroll
    for (int mt = 0; mt < 4; ++mt)
#pragma unroll
      for (int no = 0; no < 3; ++no) acc[mt][no] = MFMA_B16(a[mt], bb[no], acc[mt][no]);
  }
#pragma unroll
  for (int mt = 0; mt < 4; ++mt)
#pragma unroll
    for (int no = 0; no < 3; ++no) {
      int o = (wid * 3 + no) * 16 + lr;
      if (o >= VOC) continue;
      float bias = b2[o];
#pragma unroll
      for (int r = 0; r < 4; ++r) {
        int tg = t0 + mt * 16 + lk * 4 + r;
        if (tg < T - 1) out[((size_t)b * (T - 1) + tg) * VOC + o] = acc[mt][no][r] + bias;
      }
    }
}

extern "C" void kernel_launch(void* const* d_in, const int* in_sizes, int n_in,
                              void* d_out, int out_size, void* d_ws, size_t ws_size,
                              hipStream_t stream) {
  const int*   x      = (const int*)d_in[0];
  const float* c      = (const float*)d_in[1];
  const float* emb    = (const float*)d_in[2];
  const float* enc_w  = (const float*)d_in[3];
  const float* enc_b  = (const float*)d_in[4];
  const float* conv_w = (const float*)d_in[5];
  const float* conv_b = (const float*)d_in[6];
  const float* cond_w = (const float*)d_in[7];
  const float* cond_b = (const float*)d_in[8];
  const float* fc1_w  = (const float*)d_in[9];
  const float* fc1_b  = (const float*)d_in[10];
  const float* fc2_w  = (const float*)d_in[11];
  const float* fc2_b  = (const float*)d_in[12];
  const float* ups_w  = (const float*)d_in[13];
  const float* ups_b  = (const float*)d_in[14];
  float* out = (float*)d_out;
  (void)in_sizes; (void)n_in; (void)out_size; (void)ws_size;

  char* w = (char*)d_ws;
  bf16* hbtA  = (bf16*)w;  w += 8388608;   // bf16 (b,t,128) ping
  bf16* hbtB  = (bf16*)w;  w += 8388608;   // pong
  bf16* cuT2  = (bf16*)w;  w += 6291456;   // bf16 frag-tiled (b,1024,3,512)
  bf16* W2    = (bf16*)w;  w += 2949120;
  bf16* fc1wb = (bf16*)w;  w += 131072;
  bf16* encwb = (bf16*)w;  w += 32768;
  bf16* embb  = (bf16*)w;  w += 66560;
  bf16* w2f   = (bf16*)w;  w += 393216;    // 24 o-tiles x 16 s x 64 lanes x 8
  float* u1   = (float*)w; w += 2621440;
  float* u2   = (float*)w; w += 655360;

  prep_wconv_k<<<dim3(2880), dim3(256), 0, stream>>>(conv_w, cond_w, W2);
  prep_misc_k<<<dim3(1218), dim3(256), 0, stream>>>(fc1_w, enc_w, emb, fc2_w, fc1wb, encwb, embb, w2f);

  ups_stage_k<<<dim3(160),  dim3(256), 0, stream>>>(c,  u1, ups_w + 0,  ups_b + 0, 64);
  ups_stage_k<<<dim3(640),  dim3(256), 0, stream>>>(u1, u2, ups_w + 12, ups_b + 1, 256);
  ups_stage_k<<<dim3(2560), dim3(256), 0, stream>>>(u2, u1, ups_w + 24, ups_b + 2, 1024);
  ups4_cuT_k<<<dim3(4096),  dim3(256), 0, stream>>>(u1, ups_w + 36, ups_b + 3, cuT2);

  encode_k<<<dim3(T / 64, Bn), dim3(256), 0, stream>>>(x, embb, encwb, enc_b, hbtA);

  bf16* hti = hbtA; bf16* hto = hbtB;
  for (int p = 0; p < 12; ++p) {
    int d1 = 1 << ((2 * p) % 6);
    const bf16* wl = W2 + (size_t)p * 2 * 61440;
    const float* cb1 = conv_b + (2 * p) * 128;
    const float* db1 = cond_b + (2 * p) * 128;
    const float* cb2 = conv_b + (2 * p + 1) * 128;
    const float* db2 = cond_b + (2 * p + 1) * 128;
    dim3 g(T / 64, Bn);
    switch (d1) {
      case 1:  layer2_k<1><<<g,  dim3(512), 0, stream>>>(hti, hto, wl, cuT2, cb1, db1, cb2, db2); break;
      case 4:  layer2_k<4><<<g,  dim3(512), 0, stream>>>(hti, hto, wl, cuT2, cb1, db1, cb2, db2); break;
      case 16: layer2_k<16><<<g, dim3(512), 0, stream>>>(hti, hto, wl, cuT2, cb1, db1, cb2, db2); break;
    }
    bf16* t1 = hti; hti = hto; hto = t1;
  }

  fc12_k<<<dim3(T / 64, Bn), dim3(512), 0, stream>>>(hti, fc1wb, fc1_b, w2f, fc2_b, out);
}